// Round 22
// baseline (873.720 us; speedup 1.0000x reference)
//
#include <hip/hip_runtime.h>

#define NN 1024
#define CC 256

typedef short short8 __attribute__((ext_vector_type(8)));
typedef short short4v __attribute__((ext_vector_type(4)));
typedef float f32x4 __attribute__((ext_vector_type(4)));

// ---- output offsets (floats) ----
constexpr size_t OUT_G2P = 8ull * NN * NN;
constexpr size_t OUT_X1  = 16ull * NN * NN;
constexpr size_t OUT_X2  = OUT_X1 + 8ull * NN * CC;
constexpr size_t OUT_L   = OUT_X2 + 8ull * NN * CC;

// ---- workspace offsets (floats) ----
constexpr size_t OFF_ALU    = 0;                        // 16M floats
constexpr size_t OFF_LOGACC = 16ull * NN * NN;          // 256
constexpr size_t OFF_DEG    = OFF_LOGACC + 256;         // 16384
constexpr size_t OFF_R2N    = OFF_DEG + 16384;          // 2097152
constexpr size_t OFF_LR2    = OFF_R2N + 2097152;        // 2097152 (degp + LU panel overlay)
constexpr size_t OFF_LR1    = OFF_LR2 + 2097152;        // 32768
constexpr size_t OFF_X1P    = OFF_LR1 + 32768;          // 32768
constexpr size_t OFF_CS1    = OFF_X1P + 32768;          // 256
constexpr size_t OFF_CS2    = OFF_CS1 + 256;            // 2048
constexpr size_t OFF_BNP    = OFF_CS2 + 2048;           // 32768
constexpr size_t OFF_BNS    = OFF_BNP + 32768;          // 1024
constexpr size_t OFF_WSP    = OFF_BNS + 1024;           // 2048
constexpr size_t OFF_TG     = OFF_WSP + 2048;           // 16 x 4160 floats

// bf16 panel strides (inside OFF_LR2 overlay, dead after lgemm passes)
constexpr size_t PNL_MAT = 960 * 64;                    // shorts per matrix per side
constexpr size_t PNL_U12 = 16 * PNL_MAT;                // offset (shorts) of U12 panels

__device__ __forceinline__ unsigned short f2bf(float f) {
  unsigned u = __float_as_uint(f);
  unsigned r = (u + 0x7FFFu + ((u >> 16) & 1u)) >> 16;
  return (unsigned short)r;
}

// ============ pooling (pair tiles, symmetric): Gp tile2 = tile1^T ============
__global__ __launch_bounds__(256) void pool_pair_k(const float* __restrict__ G1,
    const float* __restrict__ G2, const float* __restrict__ U1,
    const float* __restrict__ U2, float* __restrict__ out, float* __restrict__ degp) {
  int mat = blockIdx.z, g = mat >> 3, b = mat & 7;
  const float* G = (g ? G2 : G1) + (size_t)b * NN * NN;
  const float* U = g ? U2 : U1;
  float* Gp = out + (size_t)mat * NN * NN;

  int pid = blockIdx.x;
  int ti = 0, rem = pid;
  while (rem >= 16 - ti) { rem -= 16 - ti; ++ti; }
  int tj = ti + rem;

  const int tid = threadIdx.x;
  const int tc = tid & 63, tr = tid >> 6;
  __shared__ float Wb[64][65];

  // stage Wb = W(tj,ti) tile (scalar, coalesced; conflict-free row-major stores)
  #pragma unroll
  for (int s = 0; s < 16; ++s) {
    int r = s * 4 + tr;
    size_t ib = (size_t)(tj * 64 + r) * NN + ti * 64 + tc;
    Wb[r][tc] = U[ib] * G[ib];
  }
  __syncthreads();

  // compute o1[r][tc] = 0.5*(Wa[r][tc] + Wb[tc][r]); Wa straight from global
  float o1r[16];
  #pragma unroll
  for (int s = 0; s < 16; ++s) {
    int r = s * 4 + tr;
    size_t ia = (size_t)(ti * 64 + r) * NN + tj * 64 + tc;
    float wa = U[ia] * G[ia];
    float o1 = 0.5f * (wa + Wb[tc][r]);     // transposed read, stride 65: conflict-free
    o1r[s] = o1;
    Gp[ia] = o1;
    float rs = o1;
    #pragma unroll
    for (int o = 32; o; o >>= 1) rs += __shfl_down(rs, o, 64);
    if (tc == 0)
      degp[((size_t)mat * 1024 + ti * 64 + r) * 16 + tj] = rs;
  }
  __syncthreads();

  // store o1 into LDS (reuse Wb), then emit transposed tile (Gp symmetric)
  #pragma unroll
  for (int s = 0; s < 16; ++s) Wb[s * 4 + tr][tc] = o1r[s];
  __syncthreads();
  if (ti != tj) {
    #pragma unroll
    for (int s = 0; s < 16; ++s) {
      int r = s * 4 + tr;
      float o2 = Wb[tc][r];                  // o1^T[r][tc], conflict-free
      Gp[(size_t)(tj * 64 + r) * NN + ti * 64 + tc] = o2;
      float rs = o2;
      #pragma unroll
      for (int o = 32; o; o >>= 1) rs += __shfl_down(rs, o, 64);
      if (tc == 0)
        degp[((size_t)mat * 1024 + tj * 64 + r) * 16 + ti] = rs;
    }
  }
}

// ============ prep: deg finalize (bid<64) + bn partials (bid>=64) ============
__global__ __launch_bounds__(256) void prep_k(const float* __restrict__ degp,
    float* __restrict__ deg, const float* __restrict__ R2, float* __restrict__ part) {
  if (blockIdx.x < 64) {
    int row = blockIdx.x * 256 + threadIdx.x;
    const float4* p = reinterpret_cast<const float4*>(degp + (size_t)row * 16);
    float4 a = p[0], b = p[1], c = p[2], d = p[3];
    deg[row] = a.x + a.y + a.z + a.w + b.x + b.y + b.z + b.w
             + c.x + c.y + c.z + c.w + d.x + d.y + d.z + d.w;
  } else {
    int w = blockIdx.x - 64, c = threadIdx.x;
    float s = 0.f, s2 = 0.f;
    for (int r = w * 128; r < (w + 1) * 128; ++r) {
      float x = R2[(size_t)r * CC + c];
      s += x; s2 += x * x;
    }
    part[w * 512 + c] = s;
    part[w * 512 + 256 + c] = s2;
  }
}

// ============ stats + cs2 (analytic) + cs1 in one dispatch ============
__global__ __launch_bounds__(256) void smalls_k(const float* __restrict__ part,
    const float* __restrict__ g, const float* __restrict__ bt,
    const float* __restrict__ R1, float* __restrict__ stats,
    float* __restrict__ cs2, float* __restrict__ cs1) {
  const int c = threadIdx.x;
  float s = 0.f, s2 = 0.f;
  float sb[8] = {0.f, 0.f, 0.f, 0.f, 0.f, 0.f, 0.f, 0.f};
  #pragma unroll
  for (int w = 0; w < 64; ++w) {
    float ps = part[w * 512 + c];
    s += ps; sb[w >> 3] += ps;
    s2 += part[w * 512 + 256 + c];
  }
  float mu = s / 8192.0f, var = s2 / 8192.0f - mu * mu;
  float sc = rsqrtf(var + 1e-5f) * g[c];
  float be = bt[c];
  stats[c] = mu; stats[256 + c] = sc; stats[512 + c] = be;
  #pragma unroll
  for (int b = 0; b < 8; ++b)
    cs2[b * 256 + c] = (sb[b] - 1024.0f * mu) * sc + 1024.0f * be;
  const int b1 = c >> 5, l32 = c & 31;
  float a0 = 0.f, a1 = 0.f, a2 = 0.f, a3 = 0.f;
  for (int n = l32; n < 1024; n += 32) {
    float4 v = *reinterpret_cast<const float4*>(R1 + ((size_t)b1 * 1024 + n) * 4);
    a0 += v.x; a1 += v.y; a2 += v.z; a3 += v.w;
  }
  #pragma unroll
  for (int o = 16; o; o >>= 1) {
    a0 += __shfl_down(a0, o, 32); a1 += __shfl_down(a1, o, 32);
    a2 += __shfl_down(a2, o, 32); a3 += __shfl_down(a3, o, 32);
  }
  if (l32 == 0) {
    cs1[b1 * 4 + 0] = a0; cs1[b1 * 4 + 1] = a1;
    cs1[b1 * 4 + 2] = a2; cs1[b1 * 4 + 3] = a3;
  }
}

// ============ BN apply + transposed bf16 write (fused) ============
__global__ __launch_bounds__(256) void bn_apply_tr_k(const float* __restrict__ R2,
    const float* __restrict__ stats, float* __restrict__ R2n,
    unsigned short* __restrict__ R2nt) {
  const int b = blockIdx.z, n0 = blockIdx.x * 64, c0 = blockIdx.y * 64;
  __shared__ float Ts[64][68];
  const int tid = threadIdx.x;
  #pragma unroll
  for (int s = 0; s < 4; ++s) {
    int idx = tid + s * 256, r = idx >> 4, q = idx & 15;
    const int c = c0 + q * 4;
    float4 v = *reinterpret_cast<const float4*>(R2 + ((size_t)b * NN + n0 + r) * CC + c);
    float4 mu = *reinterpret_cast<const float4*>(stats + c);
    float4 sc = *reinterpret_cast<const float4*>(stats + 256 + c);
    float4 be = *reinterpret_cast<const float4*>(stats + 512 + c);
    float4 o;
    o.x = (v.x - mu.x) * sc.x + be.x; o.y = (v.y - mu.y) * sc.y + be.y;
    o.z = (v.z - mu.z) * sc.z + be.z; o.w = (v.w - mu.w) * sc.w + be.w;
    *reinterpret_cast<float4*>(R2n + ((size_t)b * NN + n0 + r) * CC + c) = o;
    *reinterpret_cast<float4*>(&Ts[r][q * 4]) = o;
  }
  __syncthreads();
  #pragma unroll
  for (int s = 0; s < 2; ++s) {
    int idx = tid + s * 256, cc = idx >> 3, g2 = idx & 7;
    short8 o;
    #pragma unroll
    for (int e = 0; e < 8; ++e) o[e] = (short)f2bf(Ts[g2 * 8 + e][cc]);
    *reinterpret_cast<short8*>(&R2nt[((size_t)b * CC + c0 + cc) * NN + n0 + g2 * 8]) = o;
  }
}

// ============ lane-j broadcast via v_readlane (no LDS, ~4cy) ============
__device__ __forceinline__ float rl(float v, int lane) {
  return __uint_as_float(__builtin_amdgcn_readlane(__float_as_uint(v), lane));
}

// ============ wave-register unpivoted factor of x[64] rows (lane=row) ============
__device__ __forceinline__ void wave_factor64(float (&x)[64], int lane) {
  #pragma unroll
  for (int j = 0; j < 64; ++j) {
    const float pv = rl(x[j], j);
    const float pvs = (fabsf(pv) < 1e-30f) ? copysignf(1e-30f, pv) : pv;
    const float ipv = 1.0f / pvs;
    const bool act = (lane > j);
    const float lm = x[j] * ipv;
    if (act) x[j] = lm;
    #pragma unroll
    for (int c = j + 1; c < 64; ++c) {
      const float uc = rl(x[c], j);
      if (act) x[c] -= lm * uc;
    }
  }
}

// ============ step-0 diag factor: T0 + invd -> Tg, log -> logacc ============
__global__ __launch_bounds__(64, 1) void lu_diag0_k(const float* __restrict__ Gpout,
    float* __restrict__ logacc, float* __restrict__ Tg) {
  const int mat = blockIdx.x;
  const float* S = Gpout + (size_t)mat * NN * NN;
  const int tid = threadIdx.x;
  __shared__ float T[64][65];

  float x[64];
  #pragma unroll
  for (int c4 = 0; c4 < 16; ++c4) {
    float4 v = *reinterpret_cast<const float4*>(S + (size_t)tid * NN + c4 * 4);
    x[c4 * 4 + 0] = v.x; x[c4 * 4 + 1] = v.y;
    x[c4 * 4 + 2] = v.z; x[c4 * 4 + 3] = v.w;
  }
  #pragma unroll
  for (int c = 0; c < 64; ++c) if (c == tid) x[c] += 1e-3f;

  wave_factor64(x, tid);
  #pragma unroll
  for (int c = 0; c < 64; ++c) T[tid][c] = x[c];
  __syncthreads();

  float* tg = Tg + (size_t)mat * 4160;
  {
    float d = T[tid][tid];
    tg[4096 + tid] = 1.0f / ((fabsf(d) < 1e-30f) ? copysignf(1e-30f, d) : d);
    float lg = logf(fmaxf(fabsf(d), 1e-37f));
    #pragma unroll
    for (int o = 32; o; o >>= 1) lg += __shfl_down(lg, o, 64);
    if (tid == 0) logacc[mat] = lg;
  }
  #pragma unroll
  for (int i = 0; i < 16; ++i) {
    int idx = tid + i * 64, r = idx >> 4, q = idx & 15;
    *reinterpret_cast<float4*>(tg + r * 64 + q * 4) =
      *reinterpret_cast<const float4*>(&T[r][q * 4]);
  }
}

// ============ strips: solve + emit bf16 panels (MFMA-ready layouts) ============
__global__ __launch_bounds__(64, 1) void lu_strip_k(float* __restrict__ Alu,
    const float* __restrict__ Gpout, int p, const float* __restrict__ Tg,
    unsigned short* __restrict__ pnl) {
  const int mat = blockIdx.y;
  const int k0 = p * 64, base = k0 + 64;
  const int rem = NN - base;
  const int nbc = rem >> 6;
  float* A = Alu + (size_t)mat * NN * NN;
  const float* S = (p == 0) ? (Gpout + (size_t)mat * NN * NN) : A;
  const int tid = threadIdx.x;
  __shared__ float T[64][65];
  __shared__ float invd[64];

  // ---- prefetch strip values into registers (overlaps T staging) ----
  const bool isCol = ((int)blockIdx.x < nbc);
  float v[64];
  if (isCol) {
    const int col = base + blockIdx.x * 64 + tid;
    #pragma unroll
    for (int r = 0; r < 64; ++r) v[r] = S[(size_t)(k0 + r) * NN + col];
  } else {
    const int row = base + ((int)blockIdx.x - nbc) * 64 + tid;
    const float4* Ar = reinterpret_cast<const float4*>(S + (size_t)row * NN + k0);
    #pragma unroll
    for (int c4 = 0; c4 < 16; ++c4) {
      float4 t = Ar[c4];
      v[c4 * 4 + 0] = t.x; v[c4 * 4 + 1] = t.y;
      v[c4 * 4 + 2] = t.z; v[c4 * 4 + 3] = t.w;
    }
  }

  // ---- stage factored diag + invd ----
  const float* tg = Tg + (size_t)mat * 4160;
  #pragma unroll
  for (int i = 0; i < 16; ++i) {
    int idx = tid + i * 64, r = idx >> 4, q = idx & 15;
    *reinterpret_cast<float4*>(&T[r][q * 4]) =
      *reinterpret_cast<const float4*>(tg + r * 64 + q * 4);
  }
  invd[tid] = tg[4096 + tid];
  __syncthreads();

  if (isCol) {
    const int colp = blockIdx.x * 64 + tid;        // col' = col - base
    #pragma unroll
    for (int l = 0; l < 64; ++l) {
      const float ul = v[l];
      #pragma unroll
      for (int r = l + 1; r < 64; ++r) v[r] -= T[r][l] * ul;
    }
    unsigned short* dst = pnl + PNL_U12 + (size_t)mat * PNL_MAT + (size_t)colp * 64;
    #pragma unroll
    for (int k8 = 0; k8 < 8; ++k8) {
      short8 o;
      #pragma unroll
      for (int e = 0; e < 8; ++e) o[e] = (short)f2bf(v[k8 * 8 + e]);
      *reinterpret_cast<short8*>(dst + k8 * 8) = o;
    }
  } else {
    const int rowp = ((int)blockIdx.x - nbc) * 64 + tid;  // row' = row - base
    #pragma unroll
    for (int l = 0; l < 64; ++l) {
      v[l] *= invd[l];
      const float xl = v[l];
      #pragma unroll
      for (int j2 = l + 1; j2 < 64; ++j2) v[j2] -= xl * T[l][j2];
    }
    unsigned short* dst = pnl + (size_t)mat * PNL_MAT + (size_t)rowp * 64;
    #pragma unroll
    for (int k8 = 0; k8 < 8; ++k8) {
      short8 o;
      #pragma unroll
      for (int e = 0; e < 8; ++e) o[e] = (short)f2bf(v[k8 * 8 + e]);
      *reinterpret_cast<short8*>(dst + k8 * 8) = o;
    }
  }
}

// ============ Schur update + (0,0) tail: stage bf16 panels, factor next diag ============
__global__ __launch_bounds__(256, 1) void lu_gemm_mfma_k(float* __restrict__ Alu,
    const float* __restrict__ Gpout, int p, float* __restrict__ logacc,
    float* __restrict__ Tg, const unsigned short* __restrict__ pnl, int last) {
  const int mat = blockIdx.z;
  float* A = Alu + (size_t)mat * NN * NN;
  const float* S = (p == 0) ? (Gpout + (size_t)mat * NN * NN) : A;
  const int k0 = p * 64;
  const int base = k0 + 64;
  const int bx = blockIdx.x, by = blockIdx.y;
  const int r0 = base + by * 64, c0 = base + bx * 64;
  const int tid = threadIdx.x;
  const bool diagBlk = (bx == 0 && by == 0);

  __shared__ __align__(16) unsigned char smem[36864];
  unsigned short (*As)[72] = reinterpret_cast<unsigned short(*)[72]>(smem);
  unsigned short (*Bs)[72] = reinterpret_cast<unsigned short(*)[72]>(smem + 18432);
  float (*Tn)[65]          = reinterpret_cast<float(*)[65]>(smem);   // overlay post-MFMA

  // stage As/Bs: direct bf16 copies from panels (no conversion, no transpose)
  const unsigned short* pa = pnl + (size_t)mat * PNL_MAT + (size_t)by * 64 * 64;
  const unsigned short* pb = pnl + PNL_U12 + (size_t)mat * PNL_MAT + (size_t)bx * 64 * 64;
  #pragma unroll
  for (int it = 0; it < 2; ++it) {
    int idx = tid + it * 256;
    int r = idx >> 3, k8 = (idx & 7) * 8;
    *reinterpret_cast<short8*>(&As[r][k8]) =
      *reinterpret_cast<const short8*>(pa + (size_t)r * 64 + k8);
    *reinterpret_cast<short8*>(&Bs[r][k8]) =
      *reinterpret_cast<const short8*>(pb + (size_t)r * 64 + k8);
  }

  const int l = tid & 63, w = tid >> 6;
  const int wm = w >> 1, wn = w & 1;
  const int lr = l & 15, lk = l >> 4;

  // ---- prefetch epilogue orig values (own tile; overlaps staging) ----
  float orig[2][2][4];
  #pragma unroll
  for (int i = 0; i < 2; ++i) {
    #pragma unroll
    for (int j = 0; j < 2; ++j) {
      const int row0 = r0 + wm * 32 + i * 16 + lk * 4;
      const int col  = c0 + wn * 32 + j * 16 + lr;
      #pragma unroll
      for (int r = 0; r < 4; ++r) {
        const int row = row0 + r;
        float o = S[(size_t)row * NN + col];
        if (p == 0 && row == col) o += 1e-3f;
        orig[i][j][r] = o;
      }
    }
  }
  __syncthreads();

  f32x4 acc00 = {0.f, 0.f, 0.f, 0.f}, acc01 = acc00, acc10 = acc00, acc11 = acc00;
  #pragma unroll
  for (int kk = 0; kk < 64; kk += 32) {
    short8 a0 = *reinterpret_cast<const short8*>(&As[wm * 32 + lr][kk + lk * 8]);
    short8 a1 = *reinterpret_cast<const short8*>(&As[wm * 32 + 16 + lr][kk + lk * 8]);
    short8 b0 = *reinterpret_cast<const short8*>(&Bs[wn * 32 + lr][kk + lk * 8]);
    short8 b1 = *reinterpret_cast<const short8*>(&Bs[wn * 32 + 16 + lr][kk + lk * 8]);
    acc00 = __builtin_amdgcn_mfma_f32_16x16x32_bf16(a0, b0, acc00, 0, 0, 0);
    acc01 = __builtin_amdgcn_mfma_f32_16x16x32_bf16(a0, b1, acc01, 0, 0, 0);
    acc10 = __builtin_amdgcn_mfma_f32_16x16x32_bf16(a1, b0, acc10, 0, 0, 0);
    acc11 = __builtin_amdgcn_mfma_f32_16x16x32_bf16(a1, b1, acc11, 0, 0, 0);
  }
  __syncthreads();   // As/Bs dead; Tn overlay may now be written

  #pragma unroll
  for (int i = 0; i < 2; ++i) {
    #pragma unroll
    for (int j = 0; j < 2; ++j) {
      const f32x4 a = (i == 0) ? (j == 0 ? acc00 : acc01) : (j == 0 ? acc10 : acc11);
      const int rowL0 = wm * 32 + i * 16 + lk * 4;
      const int colL  = wn * 32 + j * 16 + lr;
      #pragma unroll
      for (int r = 0; r < 4; ++r) {
        const int row = r0 + rowL0 + r;
        const int col = c0 + colL;
        const float val = orig[i][j][r] - a[r];
        A[(size_t)row * NN + col] = val;
        if (diagBlk) Tn[rowL0 + r][colL] = val;
      }
    }
  }
  if (!diagBlk) return;
  __syncthreads();

  // tail: factor next diag (wave 0), log, emit Tg for next step
  if (tid < 64) {
    float x[64];
    #pragma unroll
    for (int c = 0; c < 64; ++c) x[c] = Tn[tid][c];
    wave_factor64(x, tid);
    #pragma unroll
    for (int c = 0; c < 64; ++c) Tn[tid][c] = x[c];
  }
  __syncthreads();
  float* tgw = Tg + (size_t)mat * 4160;
  if (tid < 64) {
    float d = Tn[tid][tid];
    if (!last) tgw[4096 + tid] = 1.0f / ((fabsf(d) < 1e-30f) ? copysignf(1e-30f, d) : d);
    float lg = logf(fmaxf(fabsf(d), 1e-37f));
    #pragma unroll
    for (int o = 32; o; o >>= 1) lg += __shfl_down(lg, o, 64);
    if (tid == 0) logacc[mat] += lg;
  }
  if (!last) {
    #pragma unroll
    for (int i = 0; i < 4; ++i) {
      int idx = tid + i * 256, r = idx >> 4, q = idx & 15;
      *reinterpret_cast<float4*>(tgw + r * 64 + q * 4) =
        *reinterpret_cast<const float4*>(&Tn[r][q * 4]);
    }
  }
}

// ============ thin GEMV: C=4 path ============
__global__ __launch_bounds__(256) void gemv4_k(const float* __restrict__ Gp,
    const float* __restrict__ V, const float* __restrict__ deg,
    const float* __restrict__ cs, float* __restrict__ O, int mode) {
  int wid = threadIdx.x >> 6, lane = threadIdx.x & 63;
  int row = blockIdx.x * 4 + wid;
  int b = row >> 10, i = row & 1023;
  const float* Gr = Gp + (size_t)b * NN * NN + (size_t)i * NN;
  const float* Vb = V + (size_t)b * NN * 4;
  float a0 = 0.f, a1 = 0.f, a2 = 0.f, a3 = 0.f;
  for (int k = lane; k < NN; k += 64) {
    float g = Gr[k];
    float4 v = *reinterpret_cast<const float4*>(Vb + (size_t)k * 4);
    a0 += g * v.x; a1 += g * v.y; a2 += g * v.z; a3 += g * v.w;
  }
  #pragma unroll
  for (int o = 32; o; o >>= 1) {
    a0 += __shfl_down(a0, o, 64); a1 += __shfl_down(a1, o, 64);
    a2 += __shfl_down(a2, o, 64); a3 += __shfl_down(a3, o, 64);
  }
  if (lane == 0) {
    float4 v = *reinterpret_cast<const float4*>(Vb + (size_t)i * 4);
    float dg = deg[row];
    float r0 = dg * v.x - a0, r1 = dg * v.y - a1;
    float r2 = dg * v.z - a2, r3 = dg * v.w - a3;
    if (mode) {
      r0 = 2.f * r0 + v.x + cs[b * 4 + 0];
      r1 = 2.f * r1 + v.y + cs[b * 4 + 1];
      r2 = 2.f * r2 + v.z + cs[b * 4 + 2];
      r3 = 2.f * r3 + v.w + cs[b * 4 + 3];
    }
    float4 o4 = {r0, r1, r2, r3};
    *reinterpret_cast<float4*>(O + (size_t)row * 4) = o4;
  }
}

// ============ MFMA L-apply GEMM ============
__global__ __launch_bounds__(256) void lgemm_mfma_k(const float* __restrict__ Gp,
    const unsigned short* __restrict__ Vt, const float* __restrict__ Vf,
    const float* __restrict__ deg, const float* __restrict__ cs,
    float* __restrict__ O, unsigned short* __restrict__ Ot, int mode) {
  const int b = blockIdx.z;
  const float* G = Gp + (size_t)b * NN * NN;
  const unsigned short* VT = Vt + (size_t)b * CC * NN;
  const int tid = threadIdx.x, l = tid & 63, w = tid >> 6;
  const int wm = w >> 1, wn = w & 1;
  const int m0 = blockIdx.x * 64, n0 = blockIdx.y * 64;
  const int lr = l & 15, lk = l >> 4;

  __shared__ unsigned short As[64][40];
  __shared__ unsigned short Bs[64][40];

  f32x4 acc00 = {0.f, 0.f, 0.f, 0.f}, acc01 = acc00, acc10 = acc00, acc11 = acc00;

  const int sr = tid >> 2, sk = (tid & 3) * 8;

  for (int kk = 0; kk < NN; kk += 32) {
    {
      const float* gp = &G[(size_t)(m0 + sr) * NN + kk + sk];
      float4 g0 = *reinterpret_cast<const float4*>(gp);
      float4 g1 = *reinterpret_cast<const float4*>(gp + 4);
      short8 av;
      av[0] = (short)f2bf(g0.x); av[1] = (short)f2bf(g0.y);
      av[2] = (short)f2bf(g0.z); av[3] = (short)f2bf(g0.w);
      av[4] = (short)f2bf(g1.x); av[5] = (short)f2bf(g1.y);
      av[6] = (short)f2bf(g1.z); av[7] = (short)f2bf(g1.w);
      *reinterpret_cast<short8*>(&As[sr][sk]) = av;
      short8 bv = *reinterpret_cast<const short8*>(&VT[(size_t)(n0 + sr) * NN + kk + sk]);
      *reinterpret_cast<short8*>(&Bs[sr][sk]) = bv;
    }
    __syncthreads();
    short8 a0 = *reinterpret_cast<const short8*>(&As[wm * 32 + lr][lk * 8]);
    short8 a1 = *reinterpret_cast<const short8*>(&As[wm * 32 + 16 + lr][lk * 8]);
    short8 b0 = *reinterpret_cast<const short8*>(&Bs[wn * 32 + lr][lk * 8]);
    short8 b1 = *reinterpret_cast<const short8*>(&Bs[wn * 32 + 16 + lr][lk * 8]);
    acc00 = __builtin_amdgcn_mfma_f32_16x16x32_bf16(a0, b0, acc00, 0, 0, 0);
    acc01 = __builtin_amdgcn_mfma_f32_16x16x32_bf16(a0, b1, acc01, 0, 0, 0);
    acc10 = __builtin_amdgcn_mfma_f32_16x16x32_bf16(a1, b0, acc10, 0, 0, 0);
    acc11 = __builtin_amdgcn_mfma_f32_16x16x32_bf16(a1, b1, acc11, 0, 0, 0);
    __syncthreads();
  }

  #pragma unroll
  for (int i = 0; i < 2; ++i) {
    #pragma unroll
    for (int j = 0; j < 2; ++j) {
      const f32x4 a = (i == 0) ? (j == 0 ? acc00 : acc01) : (j == 0 ? acc10 : acc11);
      const int row0 = m0 + wm * 32 + i * 16 + lk * 4;
      const int col  = n0 + wn * 32 + j * 16 + lr;
      float res[4];
      #pragma unroll
      for (int r = 0; r < 4; ++r) {
        const int row = row0 + r;
        const size_t off = ((size_t)b * NN + row) * CC + col;
        const float v = Vf[off];
        const float d = deg[(size_t)b * NN + row];
        float o = d * v - a[r];
        if (mode) o = 2.0f * o + v + cs[b * CC + col];
        O[off] = o;
        res[r] = o;
      }
      if (!mode) {
        short4v pk;
        #pragma unroll
        for (int r = 0; r < 4; ++r) pk[r] = (short)f2bf(res[r]);
        *reinterpret_cast<short4v*>(&Ot[((size_t)b * CC + col) * NN + row0]) = pk;
      }
    }
  }
}

// ============ conv1d: [B,N,4] -> [B,N,256], K=5, pad 2 ============
__global__ __launch_bounds__(256) void conv_k(const float* __restrict__ xp,
    const float* __restrict__ w, const float* __restrict__ bias,
    float* __restrict__ x1out) {
  int bn = blockIdx.x;
  int b = bn >> 10, n = bn & 1023;
  int co = threadIdx.x;
  __shared__ float xs[5][4];
  if (threadIdx.x < 20) {
    int k = threadIdx.x >> 2, ci = threadIdx.x & 3;
    int n2 = n + k - 2;
    xs[k][ci] = (n2 >= 0 && n2 < NN) ? xp[((size_t)b * NN + n2) * 4 + ci] : 0.0f;
  }
  __syncthreads();
  const float* wp = w + co * 20;
  float acc = bias[co];
  #pragma unroll
  for (int ci = 0; ci < 4; ++ci)
    #pragma unroll
    for (int k = 0; k < 5; ++k) acc += wp[ci * 5 + k] * xs[k][ci];
  x1out[((size_t)b * NN + n) * CC + co] = acc;
}

// ============ transpose x1,x2 fp32 [b][n][c] -> [arr][b][c][n] into scratch ============
__global__ __launch_bounds__(256) void transp2_k(const float* __restrict__ x1,
    const float* __restrict__ x2, float* __restrict__ dst) {
  int z = blockIdx.z, arr = z >> 3, b = z & 7;
  const float* src = arr ? x2 : x1;
  float* d = dst + (size_t)arr * 2097152;
  int n0 = blockIdx.x * 64, c0 = blockIdx.y * 64;
  __shared__ float Ts[64][68];
  int tid = threadIdx.x;
  #pragma unroll
  for (int s = 0; s < 4; ++s) {
    int idx = tid + s * 256, r = idx >> 4, q = idx & 15;
    float4 v = *reinterpret_cast<const float4*>(src + ((size_t)b * NN + n0 + r) * CC + c0 + q * 4);
    *reinterpret_cast<float4*>(&Ts[r][q * 4]) = v;
  }
  __syncthreads();
  #pragma unroll
  for (int s = 0; s < 4; ++s) {
    int idx = tid + s * 256, cc = idx >> 4, q = idx & 15;
    float4 v = {Ts[q * 4 + 0][cc], Ts[q * 4 + 1][cc], Ts[q * 4 + 2][cc], Ts[q * 4 + 3][cc]};
    *reinterpret_cast<float4*>(d + ((size_t)b * 256 + c0 + cc) * 1024 + n0 + q * 4) = v;
  }
}

// ============ Wasserstein: bitonic sort w/ register-local j<=2 stages ============
__device__ __forceinline__ void ce(float& u, float& v, bool up) {
  bool sw = (u > v) == up;
  if (sw) { float t = u; u = v; v = t; }
}

__global__ __launch_bounds__(256) void wass_k(const float* __restrict__ xt,
    float* __restrict__ part) {
  int bc = blockIdx.x;
  __shared__ float s1[1024];
  __shared__ float s2[1024];
  __shared__ float red[256];
  int t = threadIdx.x;
  {
    float4 v1 = *reinterpret_cast<const float4*>(xt + (size_t)bc * 1024 + t * 4);
    float4 v2 = *reinterpret_cast<const float4*>(xt + 2097152ull + (size_t)bc * 1024 + t * 4);
    *reinterpret_cast<float4*>(&s1[t * 4]) = v1;
    *reinterpret_cast<float4*>(&s2[t * 4]) = v2;
  }
  __syncthreads();
  for (int k = 2; k <= 1024; k <<= 1) {
    // LDS passes for strides >= 4
    for (int j = k >> 1; j >= 4; j >>= 1) {
      #pragma unroll
      for (int q = 0; q < 2; ++q) {
        int idx = t + q * 256;
        int i = ((idx & ~(j - 1)) << 1) | (idx & (j - 1));
        int l = i | j;
        bool up = ((i & k) == 0);
        float a = s1[i], bvv = s1[l];
        if ((a > bvv) == up) { s1[i] = bvv; s1[l] = a; }
        a = s2[i]; bvv = s2[l];
        if ((a > bvv) == up) { s2[i] = bvv; s2[l] = a; }
      }
      __syncthreads();
    }
    // register-local strides j=2,1 on the thread's 4 contiguous elements
    {
      float4 a = *reinterpret_cast<const float4*>(&s1[t * 4]);
      float4 b = *reinterpret_cast<const float4*>(&s2[t * 4]);
      if (k == 2) {
        ce(a.x, a.y, true);  ce(a.z, a.w, false);
        ce(b.x, b.y, true);  ce(b.z, b.w, false);
      } else {
        bool up = (((4 * t) & k) == 0);
        ce(a.x, a.z, up); ce(a.y, a.w, up);
        ce(a.x, a.y, up); ce(a.z, a.w, up);
        ce(b.x, b.z, up); ce(b.y, b.w, up);
        ce(b.x, b.y, up); ce(b.z, b.w, up);
      }
      *reinterpret_cast<float4*>(&s1[t * 4]) = a;
      *reinterpret_cast<float4*>(&s2[t * 4]) = b;
    }
    __syncthreads();
  }
  float s = 0.f;
  {
    float4 a = *reinterpret_cast<const float4*>(&s1[t * 4]);
    float4 b = *reinterpret_cast<const float4*>(&s2[t * 4]);
    s = fabsf(a.x - b.x) + fabsf(a.y - b.y) + fabsf(a.z - b.z) + fabsf(a.w - b.w);
  }
  red[t] = s;
  __syncthreads();
  for (int o = 128; o; o >>= 1) {
    if (t < o) red[t] += red[t + o];
    __syncthreads();
  }
  if (!t) part[bc] = red[0];
}

// ============ finalize losses ============
__global__ __launch_bounds__(256) void finalize_k(const float* __restrict__ logacc,
    const float* __restrict__ part, float* __restrict__ out) {
  int t = threadIdx.x;
  __shared__ double red[256];
  double s = 0.0;
  for (int i = t; i < 2048; i += 256) s += (double)part[i];
  red[t] = s;
  __syncthreads();
  for (int o = 128; o; o >>= 1) {
    if (t < o) red[t] += red[t + o];
    __syncthreads();
  }
  if (!t) {
    double l1 = 0.0, l2 = 0.0;
    for (int i = 0; i < 8; ++i) { l1 += (double)logacc[i]; l2 += (double)logacc[8 + i]; }
    out[OUT_L + 0] = (float)(-l1 / 8.0);
    out[OUT_L + 1] = (float)(-l2 / 8.0);
    out[OUT_L + 2] = (float)(red[0] / 2097152.0);
  }
}

extern "C" void kernel_launch(void* const* d_in, const int* in_sizes, int n_in,
                              void* d_out, int out_size, void* d_ws, size_t ws_size,
                              hipStream_t stream) {
  (void)in_sizes; (void)n_in; (void)out_size; (void)ws_size;
  const float* G1 = (const float*)d_in[0];
  const float* G2 = (const float*)d_in[1];
  const float* R1 = (const float*)d_in[2];
  const float* R2 = (const float*)d_in[3];
  const float* U1 = (const float*)d_in[7];
  const float* U2 = (const float*)d_in[8];
  const float* CW = (const float*)d_in[9];
  const float* CB = (const float*)d_in[10];
  const float* BG = (const float*)d_in[11];
  const float* BBt = (const float*)d_in[12];
  float* out = (float*)d_out;
  float* ws = (float*)d_ws;

  float* Alu    = ws + OFF_ALU;
  float* logacc = ws + OFF_LOGACC;
  float* deg    = ws + OFF_DEG;
  float* R2n    = ws + OFF_R2N;
  float* LR2    = ws + OFF_LR2;
  float* degp   = ws + OFF_LR2;          // overlay: dead before LR2 written
  unsigned short* PNL = (unsigned short*)(ws + OFF_LR2);  // overlay: dead after lgemm passes
  float* LR1    = ws + OFF_LR1;
  float* X1P    = ws + OFF_X1P;
  float* CS1    = ws + OFF_CS1;
  float* CS2    = ws + OFF_CS2;
  float* BNP    = ws + OFF_BNP;
  float* BNS    = ws + OFF_BNS;
  float* WSP    = ws + OFF_WSP;
  float* TG     = ws + OFF_TG;

  // bf16 scratch in not-yet-written x1 output region (freed before conv_k)
  unsigned short* R2NT = (unsigned short*)(out + OUT_X1);
  unsigned short* LR2T = (unsigned short*)(out + OUT_X1 + 1048576);

  pool_pair_k<<<dim3(136, 1, 16), 256, 0, stream>>>(G1, G2, U1, U2, out, degp);
  prep_k<<<128, 256, 0, stream>>>(degp, deg, R2, BNP);
  smalls_k<<<1, 256, 0, stream>>>(BNP, BG, BBt, R1, BNS, CS2, CS1);
  bn_apply_tr_k<<<dim3(16, 4, 8), 256, 0, stream>>>(R2, BNS, R2n, R2NT);

  // x2 path (MFMA)
  lgemm_mfma_k<<<dim3(16, 4, 8), 256, 0, stream>>>(out + OUT_G2P, R2NT, R2n,
      deg + 8192, CS2, LR2, LR2T, 0);
  lgemm_mfma_k<<<dim3(16, 4, 8), 256, 0, stream>>>(out + OUT_G2P, LR2T, LR2,
      deg + 8192, CS2, out + OUT_X2, (unsigned short*)0, 1);

  // x1 path
  gemv4_k<<<2048, 256, 0, stream>>>(out, R1, deg, CS1, LR1, 0);
  gemv4_k<<<2048, 256, 0, stream>>>(out, LR1, deg, CS1, X1P, 1);
  conv_k<<<8192, 256, 0, stream>>>(X1P, CW, CB, out + OUT_X1);

  // blocked UNPIVOTED LU (NB=64): factor-once (Tg) + bf16-panel strips + MFMA Schur
  lu_diag0_k<<<16, 64, 0, stream>>>(out, logacc, TG);
  for (int p = 0; p < 15; ++p) {
    int rem = NN - (p + 1) * 64;
    int nb = rem / 64;
    lu_strip_k<<<dim3(2 * nb, 16), 64, 0, stream>>>(Alu, out, p, TG, PNL);
    lu_gemm_mfma_k<<<dim3(nb, nb, 16), 256, 0, stream>>>(Alu, out, p, logacc,
                                                         TG, PNL, (p == 14) ? 1 : 0);
  }

  // Wasserstein: transpose x1/x2 into LU scratch (free now), coalesced sort
  transp2_k<<<dim3(16, 4, 16), 256, 0, stream>>>(out + OUT_X1, out + OUT_X2, Alu);
  wass_k<<<2048, 256, 0, stream>>>(Alu, WSP);
  finalize_k<<<1, 256, 0, stream>>>(logacc, WSP, out);
}

// Round 23
// 852.718 us; speedup vs baseline: 1.0246x; 1.0246x over previous
//
#include <hip/hip_runtime.h>

#define NN 1024
#define CC 256

typedef short short8 __attribute__((ext_vector_type(8)));
typedef short short4v __attribute__((ext_vector_type(4)));
typedef float f32x4 __attribute__((ext_vector_type(4)));

// ---- output offsets (floats) ----
constexpr size_t OUT_G2P = 8ull * NN * NN;
constexpr size_t OUT_X1  = 16ull * NN * NN;
constexpr size_t OUT_X2  = OUT_X1 + 8ull * NN * CC;
constexpr size_t OUT_L   = OUT_X2 + 8ull * NN * CC;

// ---- workspace offsets (floats) ----
constexpr size_t OFF_ALU    = 0;                        // 16M floats
constexpr size_t OFF_LOGACC = 16ull * NN * NN;          // 256
constexpr size_t OFF_DEG    = OFF_LOGACC + 256;         // 16384
constexpr size_t OFF_R2N    = OFF_DEG + 16384;          // 2097152
constexpr size_t OFF_LR2    = OFF_R2N + 2097152;        // 2097152 (degp + LU panel overlay)
constexpr size_t OFF_LR1    = OFF_LR2 + 2097152;        // 32768
constexpr size_t OFF_X1P    = OFF_LR1 + 32768;          // 32768
constexpr size_t OFF_CS1    = OFF_X1P + 32768;          // 256
constexpr size_t OFF_CS2    = OFF_CS1 + 256;            // 2048
constexpr size_t OFF_BNP    = OFF_CS2 + 2048;           // 32768
constexpr size_t OFF_BNS    = OFF_BNP + 32768;          // 1024
constexpr size_t OFF_WSP    = OFF_BNS + 1024;           // 2048
constexpr size_t OFF_TG     = OFF_WSP + 2048;           // 16 x 4160 floats

// bf16 panel strides (inside OFF_LR2 overlay, dead after lgemm passes)
constexpr size_t PNL_MAT = 960 * 64;                    // shorts per matrix per side
constexpr size_t PNL_U12 = 16 * PNL_MAT;                // offset (shorts) of U12 panels

__device__ __forceinline__ unsigned short f2bf(float f) {
  unsigned u = __float_as_uint(f);
  unsigned r = (u + 0x7FFFu + ((u >> 16) & 1u)) >> 16;
  return (unsigned short)r;
}

// ============ lane-j broadcast via v_readlane (no LDS, ~4cy) ============
__device__ __forceinline__ float rl(float v, int lane) {
  return __uint_as_float(__builtin_amdgcn_readlane(__float_as_uint(v), lane));
}

// ============ wave-register unpivoted factor of x[64] rows (lane=row) ============
__device__ __forceinline__ void wave_factor64(float (&x)[64], int lane) {
  #pragma unroll
  for (int j = 0; j < 64; ++j) {
    const float pv = rl(x[j], j);
    const float pvs = (fabsf(pv) < 1e-30f) ? copysignf(1e-30f, pv) : pv;
    const float ipv = 1.0f / pvs;
    const bool act = (lane > j);
    const float lm = x[j] * ipv;
    if (act) x[j] = lm;
    #pragma unroll
    for (int c = j + 1; c < 64; ++c) {
      const float uc = rl(x[c], j);
      if (act) x[c] -= lm * uc;
    }
  }
}

// ============ pooling (pair tiles, symmetric, float4 global IO) ============
__global__ __launch_bounds__(256) void pool_pair_k(const float* __restrict__ G1,
    const float* __restrict__ G2, const float* __restrict__ U1,
    const float* __restrict__ U2, float* __restrict__ out, float* __restrict__ degp) {
  int mat = blockIdx.z, g = mat >> 3, b = mat & 7;
  const float* G = (g ? G2 : G1) + (size_t)b * NN * NN;
  const float* U = g ? U2 : U1;
  float* Gp = out + (size_t)mat * NN * NN;

  int pid = blockIdx.x;
  int ti = 0, rem = pid;
  while (rem >= 16 - ti) { rem -= 16 - ti; ++ti; }
  int tj = ti + rem;

  const int tid = threadIdx.x;
  const int qr = tid >> 4, qc = tid & 15;
  __shared__ float Wb[64][65];

  // stage Wb = W(tj,ti): float4 global loads, scalar LDS stores (2-way = free)
  #pragma unroll
  for (int s = 0; s < 4; ++s) {
    int r = s * 16 + qr;
    size_t ib = (size_t)(tj * 64 + r) * NN + ti * 64 + qc * 4;
    float4 gv = *reinterpret_cast<const float4*>(G + ib);
    float4 uv = *reinterpret_cast<const float4*>(U + ib);
    Wb[r][qc * 4 + 0] = gv.x * uv.x; Wb[r][qc * 4 + 1] = gv.y * uv.y;
    Wb[r][qc * 4 + 2] = gv.z * uv.z; Wb[r][qc * 4 + 3] = gv.w * uv.w;
  }
  __syncthreads();

  // o1 = 0.5*(Wa + Wb^T): Wa float4 from global; transposed LDS reads (2-way free)
  float4 o1r[4];
  #pragma unroll
  for (int s = 0; s < 4; ++s) {
    int r = s * 16 + qr;
    size_t ia = (size_t)(ti * 64 + r) * NN + tj * 64 + qc * 4;
    float4 gv = *reinterpret_cast<const float4*>(G + ia);
    float4 uv = *reinterpret_cast<const float4*>(U + ia);
    float4 o;
    o.x = 0.5f * (gv.x * uv.x + Wb[qc * 4 + 0][r]);
    o.y = 0.5f * (gv.y * uv.y + Wb[qc * 4 + 1][r]);
    o.z = 0.5f * (gv.z * uv.z + Wb[qc * 4 + 2][r]);
    o.w = 0.5f * (gv.w * uv.w + Wb[qc * 4 + 3][r]);
    *reinterpret_cast<float4*>(Gp + ia) = o;
    o1r[s] = o;
  }
  __syncthreads();
  // overwrite LDS with o1 (scalar stores)
  #pragma unroll
  for (int s = 0; s < 4; ++s) {
    int r = s * 16 + qr;
    Wb[r][qc * 4 + 0] = o1r[s].x; Wb[r][qc * 4 + 1] = o1r[s].y;
    Wb[r][qc * 4 + 2] = o1r[s].z; Wb[r][qc * 4 + 3] = o1r[s].w;
  }
  __syncthreads();

  // tile 2 = o1^T (Gp symmetric), float4 writes
  if (ti != tj) {
    #pragma unroll
    for (int s = 0; s < 4; ++s) {
      int r = s * 16 + qr;
      float4 o;
      o.x = Wb[qc * 4 + 0][r]; o.y = Wb[qc * 4 + 1][r];
      o.z = Wb[qc * 4 + 2][r]; o.w = Wb[qc * 4 + 3][r];
      *reinterpret_cast<float4*>(Gp + (size_t)(tj * 64 + r) * NN + ti * 64 + qc * 4) = o;
    }
  }

  // deg partials via pipelined LDS sums (no shfl chains)
  if (tid < 64) {
    float s = 0.f;
    #pragma unroll
    for (int c = 0; c < 64; ++c) s += Wb[tid][c];
    degp[((size_t)mat * 1024 + ti * 64 + tid) * 16 + tj] = s;
  } else if (tid < 128) {
    if (ti != tj) {
      int t2 = tid - 64;
      float s = 0.f;
      #pragma unroll
      for (int c = 0; c < 64; ++c) s += Wb[c][t2];
      degp[((size_t)mat * 1024 + tj * 64 + t2) * 16 + ti] = s;
    }
  }
}

// ============ prep: deg finalize (bid<64) + bn partials (64..127) + diag0 (128..143) ============
__global__ __launch_bounds__(256) void prep_k(const float* __restrict__ degp,
    float* __restrict__ deg, const float* __restrict__ R2, float* __restrict__ part,
    const float* __restrict__ Gpout, float* __restrict__ logacc, float* __restrict__ Tg) {
  __shared__ float T[64][65];
  if (blockIdx.x < 64) {
    int row = blockIdx.x * 256 + threadIdx.x;
    const float4* p = reinterpret_cast<const float4*>(degp + (size_t)row * 16);
    float4 a = p[0], b = p[1], c = p[2], d = p[3];
    deg[row] = a.x + a.y + a.z + a.w + b.x + b.y + b.z + b.w
             + c.x + c.y + c.z + c.w + d.x + d.y + d.z + d.w;
  } else if (blockIdx.x < 128) {
    int w = blockIdx.x - 64, c = threadIdx.x;
    float s = 0.f, s2 = 0.f;
    for (int r = w * 128; r < (w + 1) * 128; ++r) {
      float x = R2[(size_t)r * CC + c];
      s += x; s2 += x * x;
    }
    part[w * 512 + c] = s;
    part[w * 512 + 256 + c] = s2;
  } else {
    // step-0 diag factor for mat = bid-128 (single wave)
    const int mat = blockIdx.x - 128;
    const int tid = threadIdx.x;
    if (tid < 64) {
      const float* S = Gpout + (size_t)mat * NN * NN;
      float x[64];
      #pragma unroll
      for (int c4 = 0; c4 < 16; ++c4) {
        float4 v = *reinterpret_cast<const float4*>(S + (size_t)tid * NN + c4 * 4);
        x[c4 * 4 + 0] = v.x; x[c4 * 4 + 1] = v.y;
        x[c4 * 4 + 2] = v.z; x[c4 * 4 + 3] = v.w;
      }
      #pragma unroll
      for (int c = 0; c < 64; ++c) if (c == tid) x[c] += 1e-3f;
      wave_factor64(x, tid);
      #pragma unroll
      for (int c = 0; c < 64; ++c) T[tid][c] = x[c];
      float* tg = Tg + (size_t)mat * 4160;
      float d = x[tid];   // T[tid][tid] == x[tid] only for c==tid; use readlane-safe form
      d = T[tid][tid];
      tg[4096 + tid] = 1.0f / ((fabsf(d) < 1e-30f) ? copysignf(1e-30f, d) : d);
      float lg = logf(fmaxf(fabsf(d), 1e-37f));
      #pragma unroll
      for (int o = 32; o; o >>= 1) lg += __shfl_down(lg, o, 64);
      if (tid == 0) logacc[mat] = lg;
      #pragma unroll
      for (int i = 0; i < 16; ++i) {
        int idx = tid + i * 64, r = idx >> 4, q = idx & 15;
        *reinterpret_cast<float4*>(tg + r * 64 + q * 4) =
          *reinterpret_cast<const float4*>(&T[r][q * 4]);
      }
    }
  }
}

// ============ stats + cs2 (analytic) + cs1 in one dispatch ============
__global__ __launch_bounds__(256) void smalls_k(const float* __restrict__ part,
    const float* __restrict__ g, const float* __restrict__ bt,
    const float* __restrict__ R1, float* __restrict__ stats,
    float* __restrict__ cs2, float* __restrict__ cs1) {
  const int c = threadIdx.x;
  float s = 0.f, s2 = 0.f;
  float sb[8] = {0.f, 0.f, 0.f, 0.f, 0.f, 0.f, 0.f, 0.f};
  #pragma unroll
  for (int w = 0; w < 64; ++w) {
    float ps = part[w * 512 + c];
    s += ps; sb[w >> 3] += ps;
    s2 += part[w * 512 + 256 + c];
  }
  float mu = s / 8192.0f, var = s2 / 8192.0f - mu * mu;
  float sc = rsqrtf(var + 1e-5f) * g[c];
  float be = bt[c];
  stats[c] = mu; stats[256 + c] = sc; stats[512 + c] = be;
  #pragma unroll
  for (int b = 0; b < 8; ++b)
    cs2[b * 256 + c] = (sb[b] - 1024.0f * mu) * sc + 1024.0f * be;
  const int b1 = c >> 5, l32 = c & 31;
  float a0 = 0.f, a1 = 0.f, a2 = 0.f, a3 = 0.f;
  for (int n = l32; n < 1024; n += 32) {
    float4 v = *reinterpret_cast<const float4*>(R1 + ((size_t)b1 * 1024 + n) * 4);
    a0 += v.x; a1 += v.y; a2 += v.z; a3 += v.w;
  }
  #pragma unroll
  for (int o = 16; o; o >>= 1) {
    a0 += __shfl_down(a0, o, 32); a1 += __shfl_down(a1, o, 32);
    a2 += __shfl_down(a2, o, 32); a3 += __shfl_down(a3, o, 32);
  }
  if (l32 == 0) {
    cs1[b1 * 4 + 0] = a0; cs1[b1 * 4 + 1] = a1;
    cs1[b1 * 4 + 2] = a2; cs1[b1 * 4 + 3] = a3;
  }
}

// ============ BN apply + transposed bf16 write (fused) ============
__global__ __launch_bounds__(256) void bn_apply_tr_k(const float* __restrict__ R2,
    const float* __restrict__ stats, float* __restrict__ R2n,
    unsigned short* __restrict__ R2nt) {
  const int b = blockIdx.z, n0 = blockIdx.x * 64, c0 = blockIdx.y * 64;
  __shared__ float Ts[64][68];
  const int tid = threadIdx.x;
  #pragma unroll
  for (int s = 0; s < 4; ++s) {
    int idx = tid + s * 256, r = idx >> 4, q = idx & 15;
    const int c = c0 + q * 4;
    float4 v = *reinterpret_cast<const float4*>(R2 + ((size_t)b * NN + n0 + r) * CC + c);
    float4 mu = *reinterpret_cast<const float4*>(stats + c);
    float4 sc = *reinterpret_cast<const float4*>(stats + 256 + c);
    float4 be = *reinterpret_cast<const float4*>(stats + 512 + c);
    float4 o;
    o.x = (v.x - mu.x) * sc.x + be.x; o.y = (v.y - mu.y) * sc.y + be.y;
    o.z = (v.z - mu.z) * sc.z + be.z; o.w = (v.w - mu.w) * sc.w + be.w;
    *reinterpret_cast<float4*>(R2n + ((size_t)b * NN + n0 + r) * CC + c) = o;
    *reinterpret_cast<float4*>(&Ts[r][q * 4]) = o;
  }
  __syncthreads();
  #pragma unroll
  for (int s = 0; s < 2; ++s) {
    int idx = tid + s * 256, cc = idx >> 3, g2 = idx & 7;
    short8 o;
    #pragma unroll
    for (int e = 0; e < 8; ++e) o[e] = (short)f2bf(Ts[g2 * 8 + e][cc]);
    *reinterpret_cast<short8*>(&R2nt[((size_t)b * CC + c0 + cc) * NN + n0 + g2 * 8]) = o;
  }
}

// ============ strips: solve + emit bf16 panels (MFMA-ready layouts) ============
__global__ __launch_bounds__(64, 1) void lu_strip_k(float* __restrict__ Alu,
    const float* __restrict__ Gpout, int p, const float* __restrict__ Tg,
    unsigned short* __restrict__ pnl) {
  const int mat = blockIdx.y;
  const int k0 = p * 64, base = k0 + 64;
  const int rem = NN - base;
  const int nbc = rem >> 6;
  float* A = Alu + (size_t)mat * NN * NN;
  const float* S = (p == 0) ? (Gpout + (size_t)mat * NN * NN) : A;
  const int tid = threadIdx.x;
  __shared__ float T[64][65];
  __shared__ float invd[64];

  // ---- prefetch strip values into registers (overlaps T staging) ----
  const bool isCol = ((int)blockIdx.x < nbc);
  float v[64];
  if (isCol) {
    const int col = base + blockIdx.x * 64 + tid;
    #pragma unroll
    for (int r = 0; r < 64; ++r) v[r] = S[(size_t)(k0 + r) * NN + col];
  } else {
    const int row = base + ((int)blockIdx.x - nbc) * 64 + tid;
    const float4* Ar = reinterpret_cast<const float4*>(S + (size_t)row * NN + k0);
    #pragma unroll
    for (int c4 = 0; c4 < 16; ++c4) {
      float4 t = Ar[c4];
      v[c4 * 4 + 0] = t.x; v[c4 * 4 + 1] = t.y;
      v[c4 * 4 + 2] = t.z; v[c4 * 4 + 3] = t.w;
    }
  }

  // ---- stage factored diag + invd ----
  const float* tg = Tg + (size_t)mat * 4160;
  #pragma unroll
  for (int i = 0; i < 16; ++i) {
    int idx = tid + i * 64, r = idx >> 4, q = idx & 15;
    *reinterpret_cast<float4*>(&T[r][q * 4]) =
      *reinterpret_cast<const float4*>(tg + r * 64 + q * 4);
  }
  invd[tid] = tg[4096 + tid];
  __syncthreads();

  if (isCol) {
    const int colp = blockIdx.x * 64 + tid;        // col' = col - base
    #pragma unroll
    for (int l = 0; l < 64; ++l) {
      const float ul = v[l];
      #pragma unroll
      for (int r = l + 1; r < 64; ++r) v[r] -= T[r][l] * ul;
    }
    unsigned short* dst = pnl + PNL_U12 + (size_t)mat * PNL_MAT + (size_t)colp * 64;
    #pragma unroll
    for (int k8 = 0; k8 < 8; ++k8) {
      short8 o;
      #pragma unroll
      for (int e = 0; e < 8; ++e) o[e] = (short)f2bf(v[k8 * 8 + e]);
      *reinterpret_cast<short8*>(dst + k8 * 8) = o;
    }
  } else {
    const int rowp = ((int)blockIdx.x - nbc) * 64 + tid;  // row' = row - base
    #pragma unroll
    for (int l = 0; l < 64; ++l) {
      v[l] *= invd[l];
      const float xl = v[l];
      #pragma unroll
      for (int j2 = l + 1; j2 < 64; ++j2) v[j2] -= xl * T[l][j2];
    }
    unsigned short* dst = pnl + (size_t)mat * PNL_MAT + (size_t)rowp * 64;
    #pragma unroll
    for (int k8 = 0; k8 < 8; ++k8) {
      short8 o;
      #pragma unroll
      for (int e = 0; e < 8; ++e) o[e] = (short)f2bf(v[k8 * 8 + e]);
      *reinterpret_cast<short8*>(dst + k8 * 8) = o;
    }
  }
}

// ============ Schur update + (0,0) tail: stage bf16 panels, factor next diag ============
__global__ __launch_bounds__(256, 1) void lu_gemm_mfma_k(float* __restrict__ Alu,
    const float* __restrict__ Gpout, int p, float* __restrict__ logacc,
    float* __restrict__ Tg, const unsigned short* __restrict__ pnl, int last) {
  const int mat = blockIdx.z;
  float* A = Alu + (size_t)mat * NN * NN;
  const float* S = (p == 0) ? (Gpout + (size_t)mat * NN * NN) : A;
  const int k0 = p * 64;
  const int base = k0 + 64;
  const int bx = blockIdx.x, by = blockIdx.y;
  const int r0 = base + by * 64, c0 = base + bx * 64;
  const int tid = threadIdx.x;
  const bool diagBlk = (bx == 0 && by == 0);

  __shared__ __align__(16) unsigned char smem[36864];
  unsigned short (*As)[72] = reinterpret_cast<unsigned short(*)[72]>(smem);
  unsigned short (*Bs)[72] = reinterpret_cast<unsigned short(*)[72]>(smem + 18432);
  float (*Tn)[65]          = reinterpret_cast<float(*)[65]>(smem);   // overlay post-MFMA

  // stage As/Bs: direct bf16 copies from panels (no conversion, no transpose)
  const unsigned short* pa = pnl + (size_t)mat * PNL_MAT + (size_t)by * 64 * 64;
  const unsigned short* pb = pnl + PNL_U12 + (size_t)mat * PNL_MAT + (size_t)bx * 64 * 64;
  #pragma unroll
  for (int it = 0; it < 2; ++it) {
    int idx = tid + it * 256;
    int r = idx >> 3, k8 = (idx & 7) * 8;
    *reinterpret_cast<short8*>(&As[r][k8]) =
      *reinterpret_cast<const short8*>(pa + (size_t)r * 64 + k8);
    *reinterpret_cast<short8*>(&Bs[r][k8]) =
      *reinterpret_cast<const short8*>(pb + (size_t)r * 64 + k8);
  }

  const int l = tid & 63, w = tid >> 6;
  const int wm = w >> 1, wn = w & 1;
  const int lr = l & 15, lk = l >> 4;

  // ---- prefetch epilogue orig values (own tile; overlaps staging) ----
  float orig[2][2][4];
  #pragma unroll
  for (int i = 0; i < 2; ++i) {
    #pragma unroll
    for (int j = 0; j < 2; ++j) {
      const int row0 = r0 + wm * 32 + i * 16 + lk * 4;
      const int col  = c0 + wn * 32 + j * 16 + lr;
      #pragma unroll
      for (int r = 0; r < 4; ++r) {
        const int row = row0 + r;
        float o = S[(size_t)row * NN + col];
        if (p == 0 && row == col) o += 1e-3f;
        orig[i][j][r] = o;
      }
    }
  }
  __syncthreads();

  f32x4 acc00 = {0.f, 0.f, 0.f, 0.f}, acc01 = acc00, acc10 = acc00, acc11 = acc00;
  #pragma unroll
  for (int kk = 0; kk < 64; kk += 32) {
    short8 a0 = *reinterpret_cast<const short8*>(&As[wm * 32 + lr][kk + lk * 8]);
    short8 a1 = *reinterpret_cast<const short8*>(&As[wm * 32 + 16 + lr][kk + lk * 8]);
    short8 b0 = *reinterpret_cast<const short8*>(&Bs[wn * 32 + lr][kk + lk * 8]);
    short8 b1 = *reinterpret_cast<const short8*>(&Bs[wn * 32 + 16 + lr][kk + lk * 8]);
    acc00 = __builtin_amdgcn_mfma_f32_16x16x32_bf16(a0, b0, acc00, 0, 0, 0);
    acc01 = __builtin_amdgcn_mfma_f32_16x16x32_bf16(a0, b1, acc01, 0, 0, 0);
    acc10 = __builtin_amdgcn_mfma_f32_16x16x32_bf16(a1, b0, acc10, 0, 0, 0);
    acc11 = __builtin_amdgcn_mfma_f32_16x16x32_bf16(a1, b1, acc11, 0, 0, 0);
  }
  __syncthreads();   // As/Bs dead; Tn overlay may now be written

  #pragma unroll
  for (int i = 0; i < 2; ++i) {
    #pragma unroll
    for (int j = 0; j < 2; ++j) {
      const f32x4 a = (i == 0) ? (j == 0 ? acc00 : acc01) : (j == 0 ? acc10 : acc11);
      const int rowL0 = wm * 32 + i * 16 + lk * 4;
      const int colL  = wn * 32 + j * 16 + lr;
      #pragma unroll
      for (int r = 0; r < 4; ++r) {
        const int row = r0 + rowL0 + r;
        const int col = c0 + colL;
        const float val = orig[i][j][r] - a[r];
        A[(size_t)row * NN + col] = val;
        if (diagBlk) Tn[rowL0 + r][colL] = val;
      }
    }
  }
  if (!diagBlk) return;
  __syncthreads();

  // tail: factor next diag (wave 0), log, emit Tg for next step
  if (tid < 64) {
    float x[64];
    #pragma unroll
    for (int c = 0; c < 64; ++c) x[c] = Tn[tid][c];
    wave_factor64(x, tid);
    #pragma unroll
    for (int c = 0; c < 64; ++c) Tn[tid][c] = x[c];
  }
  __syncthreads();
  float* tgw = Tg + (size_t)mat * 4160;
  if (tid < 64) {
    float d = Tn[tid][tid];
    if (!last) tgw[4096 + tid] = 1.0f / ((fabsf(d) < 1e-30f) ? copysignf(1e-30f, d) : d);
    float lg = logf(fmaxf(fabsf(d), 1e-37f));
    #pragma unroll
    for (int o = 32; o; o >>= 1) lg += __shfl_down(lg, o, 64);
    if (tid == 0) logacc[mat] += lg;
  }
  if (!last) {
    #pragma unroll
    for (int i = 0; i < 4; ++i) {
      int idx = tid + i * 256, r = idx >> 4, q = idx & 15;
      *reinterpret_cast<float4*>(tgw + r * 64 + q * 4) =
        *reinterpret_cast<const float4*>(&Tn[r][q * 4]);
    }
  }
}

// ============ thin GEMV: C=4 path ============
__global__ __launch_bounds__(256) void gemv4_k(const float* __restrict__ Gp,
    const float* __restrict__ V, const float* __restrict__ deg,
    const float* __restrict__ cs, float* __restrict__ O, int mode) {
  int wid = threadIdx.x >> 6, lane = threadIdx.x & 63;
  int row = blockIdx.x * 4 + wid;
  int b = row >> 10, i = row & 1023;
  const float* Gr = Gp + (size_t)b * NN * NN + (size_t)i * NN;
  const float* Vb = V + (size_t)b * NN * 4;
  float a0 = 0.f, a1 = 0.f, a2 = 0.f, a3 = 0.f;
  for (int k = lane; k < NN; k += 64) {
    float g = Gr[k];
    float4 v = *reinterpret_cast<const float4*>(Vb + (size_t)k * 4);
    a0 += g * v.x; a1 += g * v.y; a2 += g * v.z; a3 += g * v.w;
  }
  #pragma unroll
  for (int o = 32; o; o >>= 1) {
    a0 += __shfl_down(a0, o, 64); a1 += __shfl_down(a1, o, 64);
    a2 += __shfl_down(a2, o, 64); a3 += __shfl_down(a3, o, 64);
  }
  if (lane == 0) {
    float4 v = *reinterpret_cast<const float4*>(Vb + (size_t)i * 4);
    float dg = deg[row];
    float r0 = dg * v.x - a0, r1 = dg * v.y - a1;
    float r2 = dg * v.z - a2, r3 = dg * v.w - a3;
    if (mode) {
      r0 = 2.f * r0 + v.x + cs[b * 4 + 0];
      r1 = 2.f * r1 + v.y + cs[b * 4 + 1];
      r2 = 2.f * r2 + v.z + cs[b * 4 + 2];
      r3 = 2.f * r3 + v.w + cs[b * 4 + 3];
    }
    float4 o4 = {r0, r1, r2, r3};
    *reinterpret_cast<float4*>(O + (size_t)row * 4) = o4;
  }
}

// ============ MFMA L-apply GEMM ============
__global__ __launch_bounds__(256) void lgemm_mfma_k(const float* __restrict__ Gp,
    const unsigned short* __restrict__ Vt, const float* __restrict__ Vf,
    const float* __restrict__ deg, const float* __restrict__ cs,
    float* __restrict__ O, unsigned short* __restrict__ Ot, int mode) {
  const int b = blockIdx.z;
  const float* G = Gp + (size_t)b * NN * NN;
  const unsigned short* VT = Vt + (size_t)b * CC * NN;
  const int tid = threadIdx.x, l = tid & 63, w = tid >> 6;
  const int wm = w >> 1, wn = w & 1;
  const int m0 = blockIdx.x * 64, n0 = blockIdx.y * 64;
  const int lr = l & 15, lk = l >> 4;

  __shared__ unsigned short As[64][40];
  __shared__ unsigned short Bs[64][40];

  f32x4 acc00 = {0.f, 0.f, 0.f, 0.f}, acc01 = acc00, acc10 = acc00, acc11 = acc00;

  const int sr = tid >> 2, sk = (tid & 3) * 8;

  for (int kk = 0; kk < NN; kk += 32) {
    {
      const float* gp = &G[(size_t)(m0 + sr) * NN + kk + sk];
      float4 g0 = *reinterpret_cast<const float4*>(gp);
      float4 g1 = *reinterpret_cast<const float4*>(gp + 4);
      short8 av;
      av[0] = (short)f2bf(g0.x); av[1] = (short)f2bf(g0.y);
      av[2] = (short)f2bf(g0.z); av[3] = (short)f2bf(g0.w);
      av[4] = (short)f2bf(g1.x); av[5] = (short)f2bf(g1.y);
      av[6] = (short)f2bf(g1.z); av[7] = (short)f2bf(g1.w);
      *reinterpret_cast<short8*>(&As[sr][sk]) = av;
      short8 bv = *reinterpret_cast<const short8*>(&VT[(size_t)(n0 + sr) * NN + kk + sk]);
      *reinterpret_cast<short8*>(&Bs[sr][sk]) = bv;
    }
    __syncthreads();
    short8 a0 = *reinterpret_cast<const short8*>(&As[wm * 32 + lr][lk * 8]);
    short8 a1 = *reinterpret_cast<const short8*>(&As[wm * 32 + 16 + lr][lk * 8]);
    short8 b0 = *reinterpret_cast<const short8*>(&Bs[wn * 32 + lr][lk * 8]);
    short8 b1 = *reinterpret_cast<const short8*>(&Bs[wn * 32 + 16 + lr][lk * 8]);
    acc00 = __builtin_amdgcn_mfma_f32_16x16x32_bf16(a0, b0, acc00, 0, 0, 0);
    acc01 = __builtin_amdgcn_mfma_f32_16x16x32_bf16(a0, b1, acc01, 0, 0, 0);
    acc10 = __builtin_amdgcn_mfma_f32_16x16x32_bf16(a1, b0, acc10, 0, 0, 0);
    acc11 = __builtin_amdgcn_mfma_f32_16x16x32_bf16(a1, b1, acc11, 0, 0, 0);
    __syncthreads();
  }

  #pragma unroll
  for (int i = 0; i < 2; ++i) {
    #pragma unroll
    for (int j = 0; j < 2; ++j) {
      const f32x4 a = (i == 0) ? (j == 0 ? acc00 : acc01) : (j == 0 ? acc10 : acc11);
      const int row0 = m0 + wm * 32 + i * 16 + lk * 4;
      const int col  = n0 + wn * 32 + j * 16 + lr;
      float res[4];
      #pragma unroll
      for (int r = 0; r < 4; ++r) {
        const int row = row0 + r;
        const size_t off = ((size_t)b * NN + row) * CC + col;
        const float v = Vf[off];
        const float d = deg[(size_t)b * NN + row];
        float o = d * v - a[r];
        if (mode) o = 2.0f * o + v + cs[b * CC + col];
        O[off] = o;
        res[r] = o;
      }
      if (!mode) {
        short4v pk;
        #pragma unroll
        for (int r = 0; r < 4; ++r) pk[r] = (short)f2bf(res[r]);
        *reinterpret_cast<short4v*>(&Ot[((size_t)b * CC + col) * NN + row0]) = pk;
      }
    }
  }
}

// ============ conv1d: [B,N,4] -> [B,N,256], K=5, pad 2 ============
__global__ __launch_bounds__(256) void conv_k(const float* __restrict__ xp,
    const float* __restrict__ w, const float* __restrict__ bias,
    float* __restrict__ x1out) {
  int bn = blockIdx.x;
  int b = bn >> 10, n = bn & 1023;
  int co = threadIdx.x;
  __shared__ float xs[5][4];
  if (threadIdx.x < 20) {
    int k = threadIdx.x >> 2, ci = threadIdx.x & 3;
    int n2 = n + k - 2;
    xs[k][ci] = (n2 >= 0 && n2 < NN) ? xp[((size_t)b * NN + n2) * 4 + ci] : 0.0f;
  }
  __syncthreads();
  const float* wp = w + co * 20;
  float acc = bias[co];
  #pragma unroll
  for (int ci = 0; ci < 4; ++ci)
    #pragma unroll
    for (int k = 0; k < 5; ++k) acc += wp[ci * 5 + k] * xs[k][ci];
  x1out[((size_t)b * NN + n) * CC + co] = acc;
}

// ============ transpose x1,x2 fp32 [b][n][c] -> [arr][b][c][n] into scratch ============
__global__ __launch_bounds__(256) void transp2_k(const float* __restrict__ x1,
    const float* __restrict__ x2, float* __restrict__ dst) {
  int z = blockIdx.z, arr = z >> 3, b = z & 7;
  const float* src = arr ? x2 : x1;
  float* d = dst + (size_t)arr * 2097152;
  int n0 = blockIdx.x * 64, c0 = blockIdx.y * 64;
  __shared__ float Ts[64][68];
  int tid = threadIdx.x;
  #pragma unroll
  for (int s = 0; s < 4; ++s) {
    int idx = tid + s * 256, r = idx >> 4, q = idx & 15;
    float4 v = *reinterpret_cast<const float4*>(src + ((size_t)b * NN + n0 + r) * CC + c0 + q * 4);
    *reinterpret_cast<float4*>(&Ts[r][q * 4]) = v;
  }
  __syncthreads();
  #pragma unroll
  for (int s = 0; s < 4; ++s) {
    int idx = tid + s * 256, cc = idx >> 4, q = idx & 15;
    float4 v = {Ts[q * 4 + 0][cc], Ts[q * 4 + 1][cc], Ts[q * 4 + 2][cc], Ts[q * 4 + 3][cc]};
    *reinterpret_cast<float4*>(d + ((size_t)b * 256 + c0 + cc) * 1024 + n0 + q * 4) = v;
  }
}

// ============ Wasserstein: bitonic sort w/ register-local j<=2 stages ============
__device__ __forceinline__ void ce(float& u, float& v, bool up) {
  bool sw = (u > v) == up;
  if (sw) { float t = u; u = v; v = t; }
}

__global__ __launch_bounds__(256) void wass_k(const float* __restrict__ xt,
    float* __restrict__ part) {
  int bc = blockIdx.x;
  __shared__ float s1[1024];
  __shared__ float s2[1024];
  __shared__ float red[256];
  int t = threadIdx.x;
  {
    float4 v1 = *reinterpret_cast<const float4*>(xt + (size_t)bc * 1024 + t * 4);
    float4 v2 = *reinterpret_cast<const float4*>(xt + 2097152ull + (size_t)bc * 1024 + t * 4);
    *reinterpret_cast<float4*>(&s1[t * 4]) = v1;
    *reinterpret_cast<float4*>(&s2[t * 4]) = v2;
  }
  __syncthreads();
  for (int k = 2; k <= 1024; k <<= 1) {
    for (int j = k >> 1; j >= 4; j >>= 1) {
      #pragma unroll
      for (int q = 0; q < 2; ++q) {
        int idx = t + q * 256;
        int i = ((idx & ~(j - 1)) << 1) | (idx & (j - 1));
        int l = i | j;
        bool up = ((i & k) == 0);
        float a = s1[i], bvv = s1[l];
        if ((a > bvv) == up) { s1[i] = bvv; s1[l] = a; }
        a = s2[i]; bvv = s2[l];
        if ((a > bvv) == up) { s2[i] = bvv; s2[l] = a; }
      }
      __syncthreads();
    }
    {
      float4 a = *reinterpret_cast<const float4*>(&s1[t * 4]);
      float4 b = *reinterpret_cast<const float4*>(&s2[t * 4]);
      if (k == 2) {
        ce(a.x, a.y, true);  ce(a.z, a.w, false);
        ce(b.x, b.y, true);  ce(b.z, b.w, false);
      } else {
        bool up = (((4 * t) & k) == 0);
        ce(a.x, a.z, up); ce(a.y, a.w, up);
        ce(a.x, a.y, up); ce(a.z, a.w, up);
        ce(b.x, b.z, up); ce(b.y, b.w, up);
        ce(b.x, b.y, up); ce(b.z, b.w, up);
      }
      *reinterpret_cast<float4*>(&s1[t * 4]) = a;
      *reinterpret_cast<float4*>(&s2[t * 4]) = b;
    }
    __syncthreads();
  }
  float s = 0.f;
  {
    float4 a = *reinterpret_cast<const float4*>(&s1[t * 4]);
    float4 b = *reinterpret_cast<const float4*>(&s2[t * 4]);
    s = fabsf(a.x - b.x) + fabsf(a.y - b.y) + fabsf(a.z - b.z) + fabsf(a.w - b.w);
  }
  red[t] = s;
  __syncthreads();
  for (int o = 128; o; o >>= 1) {
    if (t < o) red[t] += red[t + o];
    __syncthreads();
  }
  if (!t) part[bc] = red[0];
}

// ============ finalize losses ============
__global__ __launch_bounds__(256) void finalize_k(const float* __restrict__ logacc,
    const float* __restrict__ part, float* __restrict__ out) {
  int t = threadIdx.x;
  __shared__ double red[256];
  double s = 0.0;
  for (int i = t; i < 2048; i += 256) s += (double)part[i];
  red[t] = s;
  __syncthreads();
  for (int o = 128; o; o >>= 1) {
    if (t < o) red[t] += red[t + o];
    __syncthreads();
  }
  if (!t) {
    double l1 = 0.0, l2 = 0.0;
    for (int i = 0; i < 8; ++i) { l1 += (double)logacc[i]; l2 += (double)logacc[8 + i]; }
    out[OUT_L + 0] = (float)(-l1 / 8.0);
    out[OUT_L + 1] = (float)(-l2 / 8.0);
    out[OUT_L + 2] = (float)(red[0] / 2097152.0);
  }
}

extern "C" void kernel_launch(void* const* d_in, const int* in_sizes, int n_in,
                              void* d_out, int out_size, void* d_ws, size_t ws_size,
                              hipStream_t stream) {
  (void)in_sizes; (void)n_in; (void)out_size; (void)ws_size;
  const float* G1 = (const float*)d_in[0];
  const float* G2 = (const float*)d_in[1];
  const float* R1 = (const float*)d_in[2];
  const float* R2 = (const float*)d_in[3];
  const float* U1 = (const float*)d_in[7];
  const float* U2 = (const float*)d_in[8];
  const float* CW = (const float*)d_in[9];
  const float* CB = (const float*)d_in[10];
  const float* BG = (const float*)d_in[11];
  const float* BBt = (const float*)d_in[12];
  float* out = (float*)d_out;
  float* ws = (float*)d_ws;

  float* Alu    = ws + OFF_ALU;
  float* logacc = ws + OFF_LOGACC;
  float* deg    = ws + OFF_DEG;
  float* R2n    = ws + OFF_R2N;
  float* LR2    = ws + OFF_LR2;
  float* degp   = ws + OFF_LR2;          // overlay: dead before LR2 written
  unsigned short* PNL = (unsigned short*)(ws + OFF_LR2);  // overlay: dead after lgemm passes
  float* LR1    = ws + OFF_LR1;
  float* X1P    = ws + OFF_X1P;
  float* CS1    = ws + OFF_CS1;
  float* CS2    = ws + OFF_CS2;
  float* BNP    = ws + OFF_BNP;
  float* BNS    = ws + OFF_BNS;
  float* WSP    = ws + OFF_WSP;
  float* TG     = ws + OFF_TG;

  // bf16 scratch in not-yet-written x1 output region (freed before conv_k)
  unsigned short* R2NT = (unsigned short*)(out + OUT_X1);
  unsigned short* LR2T = (unsigned short*)(out + OUT_X1 + 1048576);

  pool_pair_k<<<dim3(136, 1, 16), 256, 0, stream>>>(G1, G2, U1, U2, out, degp);
  prep_k<<<144, 256, 0, stream>>>(degp, deg, R2, BNP, out, logacc, TG);
  smalls_k<<<1, 256, 0, stream>>>(BNP, BG, BBt, R1, BNS, CS2, CS1);
  bn_apply_tr_k<<<dim3(16, 4, 8), 256, 0, stream>>>(R2, BNS, R2n, R2NT);

  // x2 path (MFMA)
  lgemm_mfma_k<<<dim3(16, 4, 8), 256, 0, stream>>>(out + OUT_G2P, R2NT, R2n,
      deg + 8192, CS2, LR2, LR2T, 0);
  lgemm_mfma_k<<<dim3(16, 4, 8), 256, 0, stream>>>(out + OUT_G2P, LR2T, LR2,
      deg + 8192, CS2, out + OUT_X2, (unsigned short*)0, 1);

  // x1 path
  gemv4_k<<<2048, 256, 0, stream>>>(out, R1, deg, CS1, LR1, 0);
  gemv4_k<<<2048, 256, 0, stream>>>(out, LR1, deg, CS1, X1P, 1);
  conv_k<<<8192, 256, 0, stream>>>(X1P, CW, CB, out + OUT_X1);

  // blocked UNPIVOTED LU (NB=64): diag0 folded into prep; bf16-panel strips + MFMA Schur
  for (int p = 0; p < 15; ++p) {
    int rem = NN - (p + 1) * 64;
    int nb = rem / 64;
    lu_strip_k<<<dim3(2 * nb, 16), 64, 0, stream>>>(Alu, out, p, TG, PNL);
    lu_gemm_mfma_k<<<dim3(nb, nb, 16), 256, 0, stream>>>(Alu, out, p, logacc,
                                                         TG, PNL, (p == 14) ? 1 : 0);
  }

  // Wasserstein: transpose x1/x2 into LU scratch (free now), coalesced sort
  transp2_k<<<dim3(16, 4, 16), 256, 0, stream>>>(out + OUT_X1, out + OUT_X2, Alu);
  wass_k<<<2048, 256, 0, stream>>>(Alu, WSP);
  finalize_k<<<1, 256, 0, stream>>>(logacc, WSP, out);
}